// Round 2
// baseline (467.973 us; speedup 1.0000x reference)
//
#include <hip/hip_runtime.h>

// B=8, S=512, DM=1024, H=16, D=64
using short8 = __attribute__((ext_vector_type(8))) short;
using f32x4  = __attribute__((ext_vector_type(4))) float;

__device__ __forceinline__ unsigned short f2bf(float x) {
    union { float f; unsigned u; } v; v.f = x;
    unsigned u = v.u;
    unsigned r = (u + 0x7fffu + ((u >> 16) & 1u)) >> 16;   // RNE
    return (unsigned short)r;
}
__device__ __forceinline__ float bf2f(unsigned short h) {
    union { unsigned u; float f; } v; v.u = ((unsigned)h) << 16;
    return v.f;
}

__device__ __forceinline__ void async16(const void* g, void* l) {
    __builtin_amdgcn_global_load_lds(
        (const __attribute__((address_space(1))) void*)g,
        (__attribute__((address_space(3))) void*)l, 16, 0, 0);
}

// ---------------------------------------------------------------------------
// fp32 -> bf16 converters (8 elems/thread)
// ---------------------------------------------------------------------------
__global__ __launch_bounds__(256) void cvt_qkv(
    const float* __restrict__ q, const float* __restrict__ k, const float* __restrict__ v,
    unsigned short* __restrict__ dst)   // 3 x 4M elems contiguous
{
    int z = blockIdx.z;
    const float* src = (z == 0) ? q : ((z == 1) ? k : v);
    unsigned short* o = dst + (size_t)z * 4194304;
    size_t i = ((size_t)blockIdx.x * 256 + threadIdx.x) * 8;
    float4 a = *(const float4*)(src + i);
    float4 b = *(const float4*)(src + i + 4);
    ushort4 lo, hi;
    lo.x = f2bf(a.x); lo.y = f2bf(a.y); lo.z = f2bf(a.z); lo.w = f2bf(a.w);
    hi.x = f2bf(b.x); hi.y = f2bf(b.y); hi.z = f2bf(b.z); hi.w = f2bf(b.w);
    *(ushort4*)(o + i) = lo;
    *(ushort4*)(o + i + 4) = hi;
}

__global__ __launch_bounds__(256) void cvt_w(
    const float* __restrict__ wq, const float* __restrict__ wk,
    const float* __restrict__ wv, const float* __restrict__ wo,
    unsigned short* __restrict__ dst)   // 4 x 1M elems contiguous
{
    int z = blockIdx.z;
    const float* src = (z == 0) ? wq : ((z == 1) ? wk : ((z == 2) ? wv : wo));
    unsigned short* o = dst + (size_t)z * 1048576;
    size_t i = ((size_t)blockIdx.x * 256 + threadIdx.x) * 8;
    float4 a = *(const float4*)(src + i);
    float4 b = *(const float4*)(src + i + 4);
    ushort4 lo, hi;
    lo.x = f2bf(a.x); lo.y = f2bf(a.y); lo.z = f2bf(a.z); lo.w = f2bf(a.w);
    hi.x = f2bf(b.x); hi.y = f2bf(b.y); hi.z = f2bf(b.z); hi.w = f2bf(b.w);
    *(ushort4*)(o + i) = lo;
    *(ushort4*)(o + i + 4) = hi;
}

// ---------------------------------------------------------------------------
// feature precompute: G2[bh][q>>2][k][q&3] = cw1 * relu(fcw.f + fcb)  (bf16)
// r-quad-packed layout: the 4 q-rows an attn lane needs are one 8B ushort4.
// ---------------------------------------------------------------------------
__global__ __launch_bounds__(256) void feat_kernel(
    const int* __restrict__ dist_adj, const float* __restrict__ spk,
    const int* __restrict__ disc_adj, const int* __restrict__ cooc_adj,
    const float* __restrict__ dist_emb, const float* __restrict__ disc_emb,
    const float* __restrict__ cooc_emb, const float* __restrict__ fcw,
    const float* __restrict__ fcb, const float* __restrict__ cw,
    unsigned short* __restrict__ G)
{
    __shared__ float s_dist[1023];
    __shared__ float s_disc[17];
    __shared__ float s_cooc[6];
    __shared__ float s_fcw[64];
    __shared__ float s_fcb[16];
    int tid = threadIdx.x;
    for (int i = tid; i < 1023; i += 256) s_dist[i] = dist_emb[i];
    if (tid < 17) s_disc[tid] = disc_emb[tid];
    if (tid < 6)  s_cooc[tid] = cooc_emb[tid];
    if (tid < 64) s_fcw[tid]  = fcw[tid];
    if (tid < 16) s_fcb[tid]  = fcb[tid];
    __syncthreads();
    float cw1 = cw[1];

    // 2048 blocks: bx = b(3b) | qq(7b) | khalf(1b)
    int bx = blockIdx.x;
    int k  = (bx & 1) * 256 + tid;
    int qq = (bx >> 1) & 127;
    int b  = bx >> 8;

    size_t abase = ((size_t)b * 512 + qq * 4) * 512 + k;
    float f0[4], f1[4], f2[4], f3[4];
#pragma unroll
    for (int r = 0; r < 4; ++r) {
        size_t a = abase + (size_t)r * 512;
        int dd = dist_adj[a];
        f1[r]  = spk[a];
        int dc = disc_adj[a];
        int cc = cooc_adj[a];
        f0[r] = s_dist[dd];
        f2[r] = dc ? s_disc[dc] : 0.f;
        f3[r] = cc ? s_cooc[cc] : 0.f;
    }

    // quad index: ((bh*128 + qq)*512 + k); ushort offset = quad*4 + (q&3)
    size_t gq = ((size_t)b * 16 * 128 + qq) * 512 + k;
#pragma unroll
    for (int h = 0; h < 16; ++h) {
        float w0 = s_fcw[h*4+0], w1 = s_fcw[h*4+1], w2 = s_fcw[h*4+2], w3 = s_fcw[h*4+3];
        float bb = s_fcb[h];
        ushort4 o;
        o.x = f2bf(fmaxf(w0*f0[0] + w1*f1[0] + w2*f2[0] + w3*f3[0] + bb, 0.f) * cw1);
        o.y = f2bf(fmaxf(w0*f0[1] + w1*f1[1] + w2*f2[1] + w3*f3[1] + bb, 0.f) * cw1);
        o.z = f2bf(fmaxf(w0*f0[2] + w1*f1[2] + w2*f2[2] + w3*f3[2] + bb, 0.f) * cw1);
        o.w = f2bf(fmaxf(w0*f0[3] + w1*f1[3] + w2*f2[3] + w3*f3[3] + bb, 0.f) * cw1);
        *(ushort4*)(G + (gq + (size_t)h * 65536) * 4) = o;
    }
}

// ---------------------------------------------------------------------------
// bf16 GEMM, m97 structure: C[m,n] = sum_k A[m,k]*W[n,k] + bias[n]
// ---------------------------------------------------------------------------
template<int OMODE>
__device__ __forceinline__ void gemm_bf16_body(
    const unsigned short* __restrict__ A, const unsigned short* __restrict__ W,
    const float* __restrict__ bias, void* __restrict__ outp, int m0, int n0)
{
    __shared__ __align__(16) unsigned short As[128 * 32];   // row-major, NO pad
    __shared__ __align__(16) unsigned short Bs[128 * 32];
    int tid = threadIdx.x;
    int lane = tid & 63, wid = tid >> 6;
    int wx = wid & 1, wy = wid >> 1;
    int lanelo = lane & 15, hi8 = (lane >> 4) * 8;
    int rowc = lane >> 2;          // row within 16-row chunk
    int colc = (lane & 3) * 8;     // k-offset (elems) within row

    f32x4 acc[4][4];
#pragma unroll
    for (int i = 0; i < 4; ++i)
#pragma unroll
        for (int j = 0; j < 4; ++j) {
            acc[i][j][0] = 0.f; acc[i][j][1] = 0.f; acc[i][j][2] = 0.f; acc[i][j][3] = 0.f;
        }

    for (int kk = 0; kk < 32; ++kk) {
        int k0 = kk * 32;
        __syncthreads();
#pragma unroll
        for (int p = 0; p < 2; ++p) {
            int c = 2 * wid + p;           // chunk 0..7
            int row = c * 16 + rowc;
            async16(A + (size_t)(m0 + row) * 1024 + k0 + colc, As + c * 512);
        }
#pragma unroll
        for (int p = 0; p < 2; ++p) {
            int c = 2 * wid + p;
            int row = c * 16 + rowc;
            async16(W + (size_t)(n0 + row) * 1024 + k0 + colc, Bs + c * 512);
        }
        __syncthreads();

        short8 af[4], bfr[4];
#pragma unroll
        for (int i = 0; i < 4; ++i)
            af[i] = *(const short8*)(As + (wy*64 + i*16 + lanelo) * 32 + hi8);
#pragma unroll
        for (int j = 0; j < 4; ++j)
            bfr[j] = *(const short8*)(Bs + (wx*64 + j*16 + lanelo) * 32 + hi8);
#pragma unroll
        for (int i = 0; i < 4; ++i)
#pragma unroll
            for (int j = 0; j < 4; ++j)
                acc[i][j] = __builtin_amdgcn_mfma_f32_16x16x32_bf16(af[i], bfr[j], acc[i][j], 0, 0, 0);
    }

    float bia[4];
#pragma unroll
    for (int j = 0; j < 4; ++j) bia[j] = bias[n0 + wx*64 + j*16 + lanelo];
#pragma unroll
    for (int i = 0; i < 4; ++i) {
        int mbase = m0 + wy*64 + i*16 + (lane >> 4) * 4;
#pragma unroll
        for (int j = 0; j < 4; ++j) {
            int n = n0 + wx*64 + j*16 + lanelo;
#pragma unroll
            for (int r = 0; r < 4; ++r) {
                int m = mbase + r;
                float val = acc[i][j][r] + bia[j];
                if (OMODE == 0) {
                    unsigned short* o = (unsigned short*)outp;
                    o[((size_t)((m >> 9) * 16 + (n >> 6)) * 512 + (m & 511)) * 64 + (n & 63)] = f2bf(val);
                } else {
                    float* o = (float*)outp;
                    o[(size_t)m * 1024 + n] = val;
                }
            }
        }
    }
}

// grid (32, 8, 3): x = m-tile (XCD-local A reuse), y = n-tile, z = tensor
__global__ __launch_bounds__(256) void gemm_qkv(
    const unsigned short* __restrict__ Abf, const unsigned short* __restrict__ Wbf,
    const float* __restrict__ bq, const float* __restrict__ bk, const float* __restrict__ bv,
    unsigned short* Qb, unsigned short* Kb, unsigned short* Vb)
{
    int z = blockIdx.z;
    const unsigned short* A = Abf + (size_t)z * 4194304;
    const unsigned short* W = Wbf + (size_t)z * 1048576;
    const float* bias = (z == 0) ? bq : ((z == 1) ? bk : bv);
    unsigned short* o = (z == 0) ? Qb : ((z == 1) ? Kb : Vb);
    gemm_bf16_body<0>(A, W, bias, o, blockIdx.x * 128, blockIdx.y * 128);
}

__global__ __launch_bounds__(256) void gemm_proj(
    const unsigned short* __restrict__ xh, const unsigned short* __restrict__ Wo,
    const float* __restrict__ bo, float* __restrict__ out)
{
    gemm_bf16_body<1>(xh, Wo, bo, out, blockIdx.x * 128, blockIdx.y * 128);
}

// ---------------------------------------------------------------------------
// Transpose V: [b,h,s,d] bf16 -> Vt [b,h,d,s] bf16
// ---------------------------------------------------------------------------
__global__ __launch_bounds__(256) void transpose_v(const unsigned short* __restrict__ Vb,
                                                   unsigned short* __restrict__ Vt)
{
    __shared__ __align__(16) unsigned short T[64][72];
    int tid = threadIdx.x;
    int s0 = blockIdx.x * 64;
    int bh = blockIdx.z * 16 + blockIdx.y;
#pragma unroll
    for (int p = 0; p < 2; ++p) {
        int c = p * 256 + tid;
        int row = c >> 3, kc = (c & 7) * 8;
        uint4 v = *(const uint4*)(Vb + ((size_t)bh * 512 + s0 + row) * 64 + kc);
        *(uint4*)&T[row][kc] = v;
    }
    __syncthreads();
#pragma unroll
    for (int p = 0; p < 2; ++p) {
        int c = p * 256 + tid;
        int d = c >> 3, sc = (c & 7) * 8;
        unsigned vv[4];
#pragma unroll
        for (int i = 0; i < 4; ++i) {
            unsigned lo = T[sc + 2*i][d];
            unsigned hi = T[sc + 2*i + 1][d];
            vv[i] = lo | (hi << 16);
        }
        uint4 o; o.x = vv[0]; o.y = vv[1]; o.z = vv[2]; o.w = vv[3];
        *(uint4*)(Vt + ((size_t)bh * 64 + d) * 512 + s0 + sc) = o;
    }
}

// ---------------------------------------------------------------------------
// Attention. LDS arena (40 KB -> 4 blocks/CU):
//   [0,9216)      Qs[64][72]        phase 1 (prologue only)
//   [9216,27648)  Ks[128][72]       phase 1 (QK^T loop)
//   [0,17408)     PT[4][16][68] f32 phase 2 (P/xh store transpose) -- overlays Qs/Ks
//   [27648,32768) Vs[64][40]        phase 3 (PV loop)
//   [32768,37888) Ps[4][16][40]     phase 3
//   [37888,39936) s_mask[512]
// Flat grid(1024) + XCD swizzle: all 8 qt-blocks of one (b,h) land on one XCD
// so K/Vt re-reads are L2 hits.
// ---------------------------------------------------------------------------
__global__ __launch_bounds__(256, 4) void attn_kernel(
    const unsigned short* __restrict__ Qb, const unsigned short* __restrict__ Kb,
    const unsigned short* __restrict__ Vt, const unsigned short* __restrict__ G,
    const int* __restrict__ mask, const float* __restrict__ cw,
    const float* __restrict__ cb, float* __restrict__ attn_out,
    unsigned short* __restrict__ xh)
{
    __shared__ __align__(16) char smem[39936];
    unsigned short (*Qs)[72]     = (unsigned short (*)[72])smem;
    unsigned short (*Ks)[72]     = (unsigned short (*)[72])(smem + 9216);
    float          (*PT)[16][68] = (float (*)[16][68])smem;          // after QK^T
    unsigned short (*Vs)[40]     = (unsigned short (*)[40])(smem + 27648);
    unsigned short (*Ps)[16][40] = (unsigned short (*)[16][40])(smem + 32768);
    int* s_mask = (int*)(smem + 37888);

    int tid = threadIdx.x;
    int lane = tid & 63, w = tid >> 6;
    int lanelo = lane & 15, hi8 = (lane >> 4) * 8;
    int hi2 = lane >> 4;

    // XCD-aware decomposition: lin%8 = XCD, groups of 8 slots share (b,h)
    int lin = blockIdx.x;
    int xcd = lin & 7;
    int s   = lin >> 3;                 // 0..127
    int bh  = xcd * 16 + (s >> 3);      // 16 heads per XCD
    int qt  = s & 7;
    int b   = bh >> 4, h = bh & 15;

    float qs  = cw[0] * 0.125f;
    float cbv = cb[0];

    s_mask[tid]       = mask[b * 512 + tid];
    s_mask[tid + 256] = mask[b * 512 + tid + 256];
#pragma unroll
    for (int p = 0; p < 2; ++p) {
        int c = p * 256 + tid;
        int row = c >> 3, kc = (c & 7) * 8;
        uint4 v = *(const uint4*)(Qb + ((size_t)bh * 512 + qt * 64 + row) * 64 + kc);
        *(uint4*)&Qs[row][kc] = v;
    }
    __syncthreads();

    short8 aq[2];
    aq[0] = *(const short8*)&Qs[w * 16 + lanelo][hi8];
    aq[1] = *(const short8*)&Qs[w * 16 + lanelo][32 + hi8];
    int qrow = qt * 64 + w * 16 + hi2 * 4;
    int qq   = qt * 16 + w * 4 + hi2;                 // q >> 2 for this lane's rows
    const unsigned short* gbase = G + ((size_t)bh * 128 + qq) * 2048;  // *512*4 ushorts

    float P[32][4];
#pragma unroll 1
    for (int kt = 0; kt < 4; ++kt) {
        // prefetch this K-tile's G quads (8B each); latency overlaps K staging
        ushort4 g[8];
#pragma unroll
        for (int j = 0; j < 8; ++j)
            g[j] = *(const ushort4*)(gbase + (kt * 8 + j) * 64 + lanelo * 4);
        __syncthreads();
#pragma unroll
        for (int p = 0; p < 4; ++p) {
            int c = p * 256 + tid;
            int row = c >> 3, kc = (c & 7) * 8;
            uint4 v = *(const uint4*)(Kb + ((size_t)bh * 512 + kt * 128 + row) * 64 + kc);
            *(uint4*)&Ks[row][kc] = v;
        }
        __syncthreads();
#pragma unroll
        for (int j = 0; j < 8; ++j) {
            short8 b0 = *(const short8*)&Ks[j * 16 + lanelo][hi8];
            short8 b1 = *(const short8*)&Ks[j * 16 + lanelo][32 + hi8];
            f32x4 acc; acc[0] = 0.f; acc[1] = 0.f; acc[2] = 0.f; acc[3] = 0.f;
            acc = __builtin_amdgcn_mfma_f32_16x16x32_bf16(aq[0], b0, acc, 0, 0, 0);
            acc = __builtin_amdgcn_mfma_f32_16x16x32_bf16(aq[1], b1, acc, 0, 0, 0);
            int jj = kt * 8 + j;
            int kcol = jj * 16 + lanelo;
            int mk = s_mask[kcol];
            float gf[4] = { bf2f(g[j].x), bf2f(g[j].y), bf2f(g[j].z), bf2f(g[j].w) };
#pragma unroll
            for (int r = 0; r < 4; ++r) {
                float e = qs * acc[r] + gf[r] + cbv;
                e = fmaxf(e, 0.f);
                P[jj][r] = mk ? __expf(e) : 0.f;
            }
        }
    }
    __syncthreads();   // Ks dead; PT (overlay) may now be written

    float inv[4];
#pragma unroll
    for (int r = 0; r < 4; ++r) {
        float s0 = 0.f;
#pragma unroll
        for (int jj = 0; jj < 32; ++jj) s0 += P[jj][r];
        s0 += __shfl_xor(s0, 1, 64);
        s0 += __shfl_xor(s0, 2, 64);
        s0 += __shfl_xor(s0, 4, 64);
        s0 += __shfl_xor(s0, 8, 64);
        inv[r] = 1.0f / s0;
    }

    // --- normalized P -> attn_out via per-wave LDS transpose, float4 stores ---
    {
        float* PTw = &PT[w][0][0];                    // [16][68]
        float* op  = attn_out + ((size_t)bh * 512 + qt * 64 + w * 16) * 512;
#pragma unroll
        for (int c = 0; c < 8; ++c) {
#pragma unroll
            for (int jc = 0; jc < 4; ++jc) {
                int jj = c * 4 + jc;
#pragma unroll
                for (int r = 0; r < 4; ++r)
                    PTw[(hi2 * 4 + r) * 68 + jc * 16 + lanelo] = P[jj][r] * inv[r];
            }
            asm volatile("s_waitcnt lgkmcnt(0)" ::: "memory");
#pragma unroll
            for (int p = 0; p < 4; ++p) {
                int row = p * 4 + hi2;
                float4 v4 = *(const float4*)&PTw[row * 68 + lanelo * 4];
                *(float4*)(op + (size_t)row * 512 + c * 64 + lanelo * 4) = v4;
            }
            asm volatile("" ::: "memory");   // keep next chunk's ds_writes after these reads
        }
    }

    f32x4 xacc[4];
#pragma unroll
    for (int jf = 0; jf < 4; ++jf) { xacc[jf][0]=0.f; xacc[jf][1]=0.f; xacc[jf][2]=0.f; xacc[jf][3]=0.f; }
#pragma unroll 1
    for (int ks = 0; ks < 16; ++ks) {
        __syncthreads();
        {
            int d = tid >> 2, kc = (tid & 3) * 8;
            uint4 v = *(const uint4*)(Vt + ((size_t)bh * 64 + d) * 512 + ks * 32 + kc);
            *(uint4*)&Vs[d][kc] = v;
        }
#pragma unroll
        for (int ff = 0; ff < 2; ++ff) {
            int f = ks * 2 + ff;
#pragma unroll
            for (int r = 0; r < 4; ++r)
                Ps[w][hi2 * 4 + r][ff * 16 + lanelo] = f2bf(P[f][r]);
        }
        __syncthreads();
        short8 ap8 = *(const short8*)&Ps[w][lanelo][hi8];
#pragma unroll
        for (int jf = 0; jf < 4; ++jf) {
            short8 bv = *(const short8*)&Vs[jf * 16 + lanelo][hi8];
            xacc[jf] = __builtin_amdgcn_mfma_f32_16x16x32_bf16(ap8, bv, xacc[jf], 0, 0, 0);
        }
    }

    // --- xh via LDS transpose (reuse PT region as ushort buffer), ushort4 stores ---
    {
        unsigned short* XT = (unsigned short*)(PT + w);   // [16][68] ushorts, per-wave
        asm volatile("" ::: "memory");
#pragma unroll
        for (int jf = 0; jf < 4; ++jf)
#pragma unroll
            for (int r = 0; r < 4; ++r)
                XT[(hi2 * 4 + r) * 68 + jf * 16 + lanelo] = f2bf(xacc[jf][r] * inv[r]);
        asm volatile("s_waitcnt lgkmcnt(0)" ::: "memory");
        unsigned short* xp = xh + ((size_t)b * 512 + qt * 64 + w * 16) * 1024 + h * 64;
#pragma unroll
        for (int p = 0; p < 4; ++p) {
            int row = p * 4 + hi2;
            ushort4 v = *(const ushort4*)&XT[row * 68 + lanelo * 4];
            *(ushort4*)(xp + (size_t)row * 1024 + lanelo * 4) = v;
        }
    }
}

// ---------------------------------------------------------------------------
extern "C" void kernel_launch(void* const* d_in, const int* in_sizes, int n_in,
                              void* d_out, int out_size, void* d_ws, size_t ws_size,
                              hipStream_t stream) {
    (void)in_sizes; (void)n_in; (void)out_size; (void)ws_size;
    const float* query    = (const float*)d_in[0];
    const float* key      = (const float*)d_in[1];
    const float* value    = (const float*)d_in[2];
    const int*   dist_adj = (const int*)d_in[3];
    const float* spk      = (const float*)d_in[4];
    const int*   disc_adj = (const int*)d_in[5];
    const int*   cooc_adj = (const int*)d_in[6];
    const int*   maskp    = (const int*)d_in[7];
    const float* Wq = (const float*)d_in[8];  const float* bq = (const float*)d_in[9];
    const float* Wk = (const float*)d_in[10]; const float* bk = (const float*)d_in[11];
    const float* Wv = (const float*)d_in[12]; const float* bv = (const float*)d_in[13];
    const float* Wo = (const float*)d_in[14]; const float* bo = (const float*)d_in[15];
    const float* dist_emb = (const float*)d_in[16];
    const float* disc_emb = (const float*)d_in[17];
    const float* cooc_emb = (const float*)d_in[18];
    const float* fcw = (const float*)d_in[19];
    const float* fcb = (const float*)d_in[20];
    const float* cw  = (const float*)d_in[21];
    const float* cbp = (const float*)d_in[22];

    char* w = (char*)d_ws;
    unsigned short* Qb  = (unsigned short*)(w);                   //  8 MB
    unsigned short* Kb  = (unsigned short*)(w + 8388608);         //  8 MB
    unsigned short* Vb  = (unsigned short*)(w + 16777216);        //  8 MB
    unsigned short* Vt  = (unsigned short*)(w + 25165824);        //  8 MB
    unsigned short* xh  = (unsigned short*)(w + 33554432);        //  8 MB
    unsigned short* G   = (unsigned short*)(w + 41943040);        // 64 MB (r-quad layout)
    unsigned short* Abf = G;                                      // alias: used before feat
    unsigned short* Wbf = (unsigned short*)(w + 109051904);       //  8 MB

    float* out_x    = (float*)d_out;
    float* attn_out = ((float*)d_out) + 4194304;

    cvt_qkv<<<dim3(2048, 1, 3), 256, 0, stream>>>(query, key, value, Abf);
    cvt_w<<<dim3(512, 1, 4), 256, 0, stream>>>(Wq, Wk, Wv, Wo, Wbf);
    gemm_qkv<<<dim3(32, 8, 3), 256, 0, stream>>>(Abf, Wbf, bq, bk, bv, Qb, Kb, Vb);
    transpose_v<<<dim3(8, 16, 8), 256, 0, stream>>>(Vb, Vt);
    feat_kernel<<<2048, 256, 0, stream>>>(dist_adj, spk, disc_adj, cooc_adj,
                                          dist_emb, disc_emb, cooc_emb, fcw, fcb, cw, G);
    attn_kernel<<<dim3(1024, 1, 1), 256, 0, stream>>>(Qb, Kb, Vt, G, maskp, cw, cbp,
                                                      attn_out, xh);
    gemm_proj<<<dim3(32, 8), 256, 0, stream>>>(xh, Wbf + 3145728, bo, out_x);
}

// Round 3
// 381.470 us; speedup vs baseline: 1.2268x; 1.2268x over previous
//
#include <hip/hip_runtime.h>

// B=8, S=512, DM=1024, H=16, D=64
using short8 = __attribute__((ext_vector_type(8))) short;
using f32x4  = __attribute__((ext_vector_type(4))) float;
typedef unsigned short u16x4 __attribute__((ext_vector_type(4)));

__device__ __forceinline__ unsigned short f2bf(float x) {
    union { float f; unsigned u; } v; v.f = x;
    unsigned u = v.u;
    unsigned r = (u + 0x7fffu + ((u >> 16) & 1u)) >> 16;   // RNE
    return (unsigned short)r;
}
__device__ __forceinline__ float bf2f(unsigned short h) {
    union { unsigned u; float f; } v; v.u = ((unsigned)h) << 16;
    return v.f;
}

__device__ __forceinline__ void async16(const void* g, void* l) {
    __builtin_amdgcn_global_load_lds(
        (const __attribute__((address_space(1))) void*)g,
        (__attribute__((address_space(3))) void*)l, 16, 0, 0);
}

// ---------------------------------------------------------------------------
// fp32 -> bf16 converters (8 elems/thread)
// ---------------------------------------------------------------------------
__global__ __launch_bounds__(256) void cvt_qkv(
    const float* __restrict__ q, const float* __restrict__ k, const float* __restrict__ v,
    unsigned short* __restrict__ dst)   // 3 x 4M elems contiguous
{
    int z = blockIdx.z;
    const float* src = (z == 0) ? q : ((z == 1) ? k : v);
    unsigned short* o = dst + (size_t)z * 4194304;
    size_t i = ((size_t)blockIdx.x * 256 + threadIdx.x) * 8;
    float4 a = *(const float4*)(src + i);
    float4 b = *(const float4*)(src + i + 4);
    ushort4 lo, hi;
    lo.x = f2bf(a.x); lo.y = f2bf(a.y); lo.z = f2bf(a.z); lo.w = f2bf(a.w);
    hi.x = f2bf(b.x); hi.y = f2bf(b.y); hi.z = f2bf(b.z); hi.w = f2bf(b.w);
    *(ushort4*)(o + i) = lo;
    *(ushort4*)(o + i + 4) = hi;
}

__global__ __launch_bounds__(256) void cvt_w(
    const float* __restrict__ wq, const float* __restrict__ wk,
    const float* __restrict__ wv, const float* __restrict__ wo,
    unsigned short* __restrict__ dst)   // 4 x 1M elems contiguous
{
    int z = blockIdx.z;
    const float* src = (z == 0) ? wq : ((z == 1) ? wk : ((z == 2) ? wv : wo));
    unsigned short* o = dst + (size_t)z * 1048576;
    size_t i = ((size_t)blockIdx.x * 256 + threadIdx.x) * 8;
    float4 a = *(const float4*)(src + i);
    float4 b = *(const float4*)(src + i + 4);
    ushort4 lo, hi;
    lo.x = f2bf(a.x); lo.y = f2bf(a.y); lo.z = f2bf(a.z); lo.w = f2bf(a.w);
    hi.x = f2bf(b.x); hi.y = f2bf(b.y); hi.z = f2bf(b.z); hi.w = f2bf(b.w);
    *(ushort4*)(o + i) = lo;
    *(ushort4*)(o + i + 4) = hi;
}

// ---------------------------------------------------------------------------
// feature precompute: G2[bh][q>>2][k][q&3] = cw1 * relu(fcw.f + fcb)  (bf16)
// r-quad-packed layout: the 4 q-rows an attn lane needs are one 8B ushort4.
// ---------------------------------------------------------------------------
__global__ __launch_bounds__(256) void feat_kernel(
    const int* __restrict__ dist_adj, const float* __restrict__ spk,
    const int* __restrict__ disc_adj, const int* __restrict__ cooc_adj,
    const float* __restrict__ dist_emb, const float* __restrict__ disc_emb,
    const float* __restrict__ cooc_emb, const float* __restrict__ fcw,
    const float* __restrict__ fcb, const float* __restrict__ cw,
    unsigned short* __restrict__ G)
{
    __shared__ float s_dist[1023];
    __shared__ float s_disc[17];
    __shared__ float s_cooc[6];
    __shared__ float s_fcw[64];
    __shared__ float s_fcb[16];
    int tid = threadIdx.x;
    for (int i = tid; i < 1023; i += 256) s_dist[i] = dist_emb[i];
    if (tid < 17) s_disc[tid] = disc_emb[tid];
    if (tid < 6)  s_cooc[tid] = cooc_emb[tid];
    if (tid < 64) s_fcw[tid]  = fcw[tid];
    if (tid < 16) s_fcb[tid]  = fcb[tid];
    __syncthreads();
    float cw1 = cw[1];

    // 2048 blocks: bx = b(3b) | qq(7b) | khalf(1b)
    int bx = blockIdx.x;
    int k  = (bx & 1) * 256 + tid;
    int qq = (bx >> 1) & 127;
    int b  = bx >> 8;

    size_t abase = ((size_t)b * 512 + qq * 4) * 512 + k;
    float f0[4], f1[4], f2[4], f3[4];
#pragma unroll
    for (int r = 0; r < 4; ++r) {
        size_t a = abase + (size_t)r * 512;
        int dd = dist_adj[a];
        f1[r]  = spk[a];
        int dc = disc_adj[a];
        int cc = cooc_adj[a];
        f0[r] = s_dist[dd];
        f2[r] = dc ? s_disc[dc] : 0.f;
        f3[r] = cc ? s_cooc[cc] : 0.f;
    }

    // quad index: ((bh*128 + qq)*512 + k); ushort offset = quad*4 + (q&3)
    size_t gq = ((size_t)b * 16 * 128 + qq) * 512 + k;
#pragma unroll
    for (int h = 0; h < 16; ++h) {
        float w0 = s_fcw[h*4+0], w1 = s_fcw[h*4+1], w2 = s_fcw[h*4+2], w3 = s_fcw[h*4+3];
        float bb = s_fcb[h];
        ushort4 o;
        o.x = f2bf(fmaxf(w0*f0[0] + w1*f1[0] + w2*f2[0] + w3*f3[0] + bb, 0.f) * cw1);
        o.y = f2bf(fmaxf(w0*f0[1] + w1*f1[1] + w2*f2[1] + w3*f3[1] + bb, 0.f) * cw1);
        o.z = f2bf(fmaxf(w0*f0[2] + w1*f1[2] + w2*f2[2] + w3*f3[2] + bb, 0.f) * cw1);
        o.w = f2bf(fmaxf(w0*f0[3] + w1*f1[3] + w2*f2[3] + w3*f3[3] + bb, 0.f) * cw1);
        *(ushort4*)(G + (gq + (size_t)h * 65536) * 4) = o;
    }
}

// ---------------------------------------------------------------------------
// bf16 GEMM, m97 structure: C[m,n] = sum_k A[m,k]*W[n,k] + bias[n]
// ---------------------------------------------------------------------------
template<int OMODE>
__device__ __forceinline__ void gemm_bf16_body(
    const unsigned short* __restrict__ A, const unsigned short* __restrict__ W,
    const float* __restrict__ bias, void* __restrict__ outp, int m0, int n0)
{
    __shared__ __align__(16) unsigned short As[128 * 32];   // row-major, NO pad
    __shared__ __align__(16) unsigned short Bs[128 * 32];
    int tid = threadIdx.x;
    int lane = tid & 63, wid = tid >> 6;
    int wx = wid & 1, wy = wid >> 1;
    int lanelo = lane & 15, hi8 = (lane >> 4) * 8;
    int rowc = lane >> 2;          // row within 16-row chunk
    int colc = (lane & 3) * 8;     // k-offset (elems) within row

    f32x4 acc[4][4];
#pragma unroll
    for (int i = 0; i < 4; ++i)
#pragma unroll
        for (int j = 0; j < 4; ++j) {
            acc[i][j][0] = 0.f; acc[i][j][1] = 0.f; acc[i][j][2] = 0.f; acc[i][j][3] = 0.f;
        }

    for (int kk = 0; kk < 32; ++kk) {
        int k0 = kk * 32;
        __syncthreads();
#pragma unroll
        for (int p = 0; p < 2; ++p) {
            int c = 2 * wid + p;           // chunk 0..7
            int row = c * 16 + rowc;
            async16(A + (size_t)(m0 + row) * 1024 + k0 + colc, As + c * 512);
        }
#pragma unroll
        for (int p = 0; p < 2; ++p) {
            int c = 2 * wid + p;
            int row = c * 16 + rowc;
            async16(W + (size_t)(n0 + row) * 1024 + k0 + colc, Bs + c * 512);
        }
        __syncthreads();

        short8 af[4], bfr[4];
#pragma unroll
        for (int i = 0; i < 4; ++i)
            af[i] = *(const short8*)(As + (wy*64 + i*16 + lanelo) * 32 + hi8);
#pragma unroll
        for (int j = 0; j < 4; ++j)
            bfr[j] = *(const short8*)(Bs + (wx*64 + j*16 + lanelo) * 32 + hi8);
#pragma unroll
        for (int i = 0; i < 4; ++i)
#pragma unroll
            for (int j = 0; j < 4; ++j)
                acc[i][j] = __builtin_amdgcn_mfma_f32_16x16x32_bf16(af[i], bfr[j], acc[i][j], 0, 0, 0);
    }

    float bia[4];
#pragma unroll
    for (int j = 0; j < 4; ++j) bia[j] = bias[n0 + wx*64 + j*16 + lanelo];
#pragma unroll
    for (int i = 0; i < 4; ++i) {
        int mbase = m0 + wy*64 + i*16 + (lane >> 4) * 4;
#pragma unroll
        for (int j = 0; j < 4; ++j) {
            int n = n0 + wx*64 + j*16 + lanelo;
#pragma unroll
            for (int r = 0; r < 4; ++r) {
                int m = mbase + r;
                float val = acc[i][j][r] + bia[j];
                if (OMODE == 0) {
                    unsigned short* o = (unsigned short*)outp;
                    o[((size_t)((m >> 9) * 16 + (n >> 6)) * 512 + (m & 511)) * 64 + (n & 63)] = f2bf(val);
                } else {
                    float* o = (float*)outp;
                    o[(size_t)m * 1024 + n] = val;
                }
            }
        }
    }
}

// grid (32, 8, 3): x = m-tile (XCD-local A reuse), y = n-tile, z = tensor
__global__ __launch_bounds__(256) void gemm_qkv(
    const unsigned short* __restrict__ Abf, const unsigned short* __restrict__ Wbf,
    const float* __restrict__ bq, const float* __restrict__ bk, const float* __restrict__ bv,
    unsigned short* Qb, unsigned short* Kb, unsigned short* Vb)
{
    int z = blockIdx.z;
    const unsigned short* A = Abf + (size_t)z * 4194304;
    const unsigned short* W = Wbf + (size_t)z * 1048576;
    const float* bias = (z == 0) ? bq : ((z == 1) ? bk : bv);
    unsigned short* o = (z == 0) ? Qb : ((z == 1) ? Kb : Vb);
    gemm_bf16_body<0>(A, W, bias, o, blockIdx.x * 128, blockIdx.y * 128);
}

__global__ __launch_bounds__(256) void gemm_proj(
    const unsigned short* __restrict__ xh, const unsigned short* __restrict__ Wo,
    const float* __restrict__ bo, float* __restrict__ out)
{
    gemm_bf16_body<1>(xh, Wo, bo, out, blockIdx.x * 128, blockIdx.y * 128);
}

// ---------------------------------------------------------------------------
// Transpose V: [b,h,s,d] bf16 -> Vt [b,h,d,s] bf16
// ---------------------------------------------------------------------------
__global__ __launch_bounds__(256) void transpose_v(const unsigned short* __restrict__ Vb,
                                                   unsigned short* __restrict__ Vt)
{
    __shared__ __align__(16) unsigned short T[64][72];
    int tid = threadIdx.x;
    int s0 = blockIdx.x * 64;
    int bh = blockIdx.z * 16 + blockIdx.y;
#pragma unroll
    for (int p = 0; p < 2; ++p) {
        int c = p * 256 + tid;
        int row = c >> 3, kc = (c & 7) * 8;
        uint4 v = *(const uint4*)(Vb + ((size_t)bh * 512 + s0 + row) * 64 + kc);
        *(uint4*)&T[row][kc] = v;
    }
    __syncthreads();
#pragma unroll
    for (int p = 0; p < 2; ++p) {
        int c = p * 256 + tid;
        int d = c >> 3, sc = (c & 7) * 8;
        unsigned vv[4];
#pragma unroll
        for (int i = 0; i < 4; ++i) {
            unsigned lo = T[sc + 2*i][d];
            unsigned hi = T[sc + 2*i + 1][d];
            vv[i] = lo | (hi << 16);
        }
        uint4 o; o.x = vv[0]; o.y = vv[1]; o.z = vv[2]; o.w = vv[3];
        *(uint4*)(Vt + ((size_t)bh * 64 + d) * 512 + s0 + sc) = o;
    }
}

// ---------------------------------------------------------------------------
// Attention. Key change this round: P[32][4] MUST live in registers.
//  - full unroll of kt/ks loops -> all P indices compile-time (no scratch)
//  - __launch_bounds__(256, 2) -> 256-VGPR cap (2 blocks/CU; that's fine,
//    the latency we were hiding before was the scratch itself)
//  - direct scalar P stores (64B segments = line-granular), nontemporal
//  - G loads nontemporal (streamed once; stop thrashing L2 so K/Vt re-reads hit)
// ---------------------------------------------------------------------------
__global__ __launch_bounds__(256, 2) void attn_kernel(
    const unsigned short* __restrict__ Qb, const unsigned short* __restrict__ Kb,
    const unsigned short* __restrict__ Vt, const unsigned short* __restrict__ G,
    const int* __restrict__ mask, const float* __restrict__ cw,
    const float* __restrict__ cb, float* __restrict__ attn_out,
    unsigned short* __restrict__ xh)
{
    __shared__ __align__(16) unsigned short Qs[64][72];
    __shared__ __align__(16) unsigned short Ks[128][72];
    __shared__ __align__(16) unsigned short Vs[64][40];
    __shared__ __align__(16) unsigned short Ps[4][16][40];
    __shared__ int s_mask[512];

    int tid = threadIdx.x;
    int lane = tid & 63, w = tid >> 6;
    int lanelo = lane & 15, hi8 = (lane >> 4) * 8;
    int hi2 = lane >> 4;

    // XCD-aware decomposition: lin%8 = XCD, groups of 8 slots share (b,h)
    int lin = blockIdx.x;
    int xcd = lin & 7;
    int s   = lin >> 3;                 // 0..127
    int bh  = xcd * 16 + (s >> 3);      // 16 heads per XCD
    int qt  = s & 7;
    int b   = bh >> 4, h = bh & 15;

    float qs  = cw[0] * 0.125f;
    float cbv = cb[0];

    s_mask[tid]       = mask[b * 512 + tid];
    s_mask[tid + 256] = mask[b * 512 + tid + 256];
#pragma unroll
    for (int p = 0; p < 2; ++p) {
        int c = p * 256 + tid;
        int row = c >> 3, kc = (c & 7) * 8;
        uint4 v = *(const uint4*)(Qb + ((size_t)bh * 512 + qt * 64 + row) * 64 + kc);
        *(uint4*)&Qs[row][kc] = v;
    }
    __syncthreads();

    short8 aq[2];
    aq[0] = *(const short8*)&Qs[w * 16 + lanelo][hi8];
    aq[1] = *(const short8*)&Qs[w * 16 + lanelo][32 + hi8];
    int qrow = qt * 64 + w * 16 + hi2 * 4;
    int qq   = qt * 16 + w * 4 + hi2;                 // q >> 2 for this lane's rows
    const unsigned short* gbase = G + ((size_t)bh * 128 + qq) * 2048;  // *512*4 ushorts

    float P[32][4];
#pragma unroll
    for (int kt = 0; kt < 4; ++kt) {
        // prefetch this K-tile's G quads (8B each, nontemporal); latency
        // overlaps K staging
        u16x4 g[8];
#pragma unroll
        for (int j = 0; j < 8; ++j)
            g[j] = __builtin_nontemporal_load(
                (const u16x4*)(gbase + (kt * 8 + j) * 64 + lanelo * 4));
        __syncthreads();
#pragma unroll
        for (int p = 0; p < 4; ++p) {
            int c = p * 256 + tid;
            int row = c >> 3, kc = (c & 7) * 8;
            uint4 v = *(const uint4*)(Kb + ((size_t)bh * 512 + kt * 128 + row) * 64 + kc);
            *(uint4*)&Ks[row][kc] = v;
        }
        __syncthreads();
#pragma unroll
        for (int j = 0; j < 8; ++j) {
            short8 b0 = *(const short8*)&Ks[j * 16 + lanelo][hi8];
            short8 b1 = *(const short8*)&Ks[j * 16 + lanelo][32 + hi8];
            f32x4 acc; acc[0] = 0.f; acc[1] = 0.f; acc[2] = 0.f; acc[3] = 0.f;
            acc = __builtin_amdgcn_mfma_f32_16x16x32_bf16(aq[0], b0, acc, 0, 0, 0);
            acc = __builtin_amdgcn_mfma_f32_16x16x32_bf16(aq[1], b1, acc, 0, 0, 0);
            int jj = kt * 8 + j;
            int kcol = jj * 16 + lanelo;
            int mk = s_mask[kcol];
            float gf[4] = { bf2f((unsigned short)g[j][0]), bf2f((unsigned short)g[j][1]),
                            bf2f((unsigned short)g[j][2]), bf2f((unsigned short)g[j][3]) };
#pragma unroll
            for (int r = 0; r < 4; ++r) {
                float e = qs * acc[r] + gf[r] + cbv;
                e = fmaxf(e, 0.f);
                P[jj][r] = mk ? __expf(e) : 0.f;
            }
        }
    }

    float inv[4];
#pragma unroll
    for (int r = 0; r < 4; ++r) {
        float s0 = 0.f;
#pragma unroll
        for (int jj = 0; jj < 32; ++jj) s0 += P[jj][r];
        s0 += __shfl_xor(s0, 1, 64);
        s0 += __shfl_xor(s0, 2, 64);
        s0 += __shfl_xor(s0, 4, 64);
        s0 += __shfl_xor(s0, 8, 64);
        inv[r] = 1.0f / s0;
    }

    // normalized P -> attn_out: direct scalar stores. Each 16-lane group
    // writes a 64B contiguous segment (full line); fire-and-forget; nt to
    // avoid polluting L2 (attn_out is never re-read).
    {
        float* ap = attn_out + ((size_t)bh * 512 + qrow) * 512 + lanelo;
#pragma unroll
        for (int jj = 0; jj < 32; ++jj)
#pragma unroll
            for (int r = 0; r < 4; ++r)
                __builtin_nontemporal_store(P[jj][r] * inv[r],
                                            ap + (size_t)r * 512 + jj * 16);
    }

    f32x4 xacc[4];
#pragma unroll
    for (int jf = 0; jf < 4; ++jf) { xacc[jf][0]=0.f; xacc[jf][1]=0.f; xacc[jf][2]=0.f; xacc[jf][3]=0.f; }
#pragma unroll
    for (int ks = 0; ks < 16; ++ks) {
        __syncthreads();
        {
            int d = tid >> 2, kc = (tid & 3) * 8;
            uint4 v = *(const uint4*)(Vt + ((size_t)bh * 64 + d) * 512 + ks * 32 + kc);
            *(uint4*)&Vs[d][kc] = v;
        }
#pragma unroll
        for (int ff = 0; ff < 2; ++ff) {
            int f = ks * 2 + ff;
#pragma unroll
            for (int r = 0; r < 4; ++r)
                Ps[w][hi2 * 4 + r][ff * 16 + lanelo] = f2bf(P[f][r]);
        }
        __syncthreads();
        short8 ap8 = *(const short8*)&Ps[w][lanelo][hi8];
#pragma unroll
        for (int jf = 0; jf < 4; ++jf) {
            short8 bv = *(const short8*)&Vs[jf * 16 + lanelo][hi8];
            xacc[jf] = __builtin_amdgcn_mfma_f32_16x16x32_bf16(ap8, bv, xacc[jf], 0, 0, 0);
        }
    }

#pragma unroll
    for (int jf = 0; jf < 4; ++jf) {
        int d = jf * 16 + lanelo;
#pragma unroll
        for (int r = 0; r < 4; ++r) {
            float val = xacc[jf][r] * inv[r];
            xh[((size_t)b * 512 + qrow + r) * 1024 + h * 64 + d] = f2bf(val);
        }
    }
}

// ---------------------------------------------------------------------------
extern "C" void kernel_launch(void* const* d_in, const int* in_sizes, int n_in,
                              void* d_out, int out_size, void* d_ws, size_t ws_size,
                              hipStream_t stream) {
    (void)in_sizes; (void)n_in; (void)out_size; (void)ws_size;
    const float* query    = (const float*)d_in[0];
    const float* key      = (const float*)d_in[1];
    const float* value    = (const float*)d_in[2];
    const int*   dist_adj = (const int*)d_in[3];
    const float* spk      = (const float*)d_in[4];
    const int*   disc_adj = (const int*)d_in[5];
    const int*   cooc_adj = (const int*)d_in[6];
    const int*   maskp    = (const int*)d_in[7];
    const float* Wq = (const float*)d_in[8];  const float* bq = (const float*)d_in[9];
    const float* Wk = (const float*)d_in[10]; const float* bk = (const float*)d_in[11];
    const float* Wv = (const float*)d_in[12]; const float* bv = (const float*)d_in[13];
    const float* Wo = (const float*)d_in[14]; const float* bo = (const float*)d_in[15];
    const float* dist_emb = (const float*)d_in[16];
    const float* disc_emb = (const float*)d_in[17];
    const float* cooc_emb = (const float*)d_in[18];
    const float* fcw = (const float*)d_in[19];
    const float* fcb = (const float*)d_in[20];
    const float* cw  = (const float*)d_in[21];
    const float* cbp = (const float*)d_in[22];

    char* w = (char*)d_ws;
    unsigned short* Qb  = (unsigned short*)(w);                   //  8 MB
    unsigned short* Kb  = (unsigned short*)(w + 8388608);         //  8 MB
    unsigned short* Vb  = (unsigned short*)(w + 16777216);        //  8 MB
    unsigned short* Vt  = (unsigned short*)(w + 25165824);        //  8 MB
    unsigned short* xh  = (unsigned short*)(w + 33554432);        //  8 MB
    unsigned short* G   = (unsigned short*)(w + 41943040);        // 64 MB (r-quad layout)
    unsigned short* Abf = G;                                      // alias: used before feat
    unsigned short* Wbf = (unsigned short*)(w + 109051904);       //  8 MB

    float* out_x    = (float*)d_out;
    float* attn_out = ((float*)d_out) + 4194304;

    cvt_qkv<<<dim3(2048, 1, 3), 256, 0, stream>>>(query, key, value, Abf);
    cvt_w<<<dim3(512, 1, 4), 256, 0, stream>>>(Wq, Wk, Wv, Wo, Wbf);
    gemm_qkv<<<dim3(32, 8, 3), 256, 0, stream>>>(Abf, Wbf, bq, bk, bv, Qb, Kb, Vb);
    transpose_v<<<dim3(8, 16, 8), 256, 0, stream>>>(Vb, Vt);
    feat_kernel<<<2048, 256, 0, stream>>>(dist_adj, spk, disc_adj, cooc_adj,
                                          dist_emb, disc_emb, cooc_emb, fcw, fcb, cw, G);
    attn_kernel<<<dim3(1024, 1, 1), 256, 0, stream>>>(Qb, Kb, Vt, G, maskp, cw, cbp,
                                                      attn_out, xh);
    gemm_proj<<<dim3(32, 8), 256, 0, stream>>>(xh, Wbf + 3145728, bo, out_x);
}